// Round 3
// baseline (32.989 us; speedup 1.0000x reference)
//
#include <hip/hip_runtime.h>
#include <math.h>

// EigenMatrixGenerator: N=40 grid, state S=4800.
// Analytic collapse: A = Re(P diag(L) P^H) with P made of diagonal blocks
//   [I I I; 0 D(v2) D(v3); 0 D(v2) D(v3)], v3 = -conj(v2), lam3 = conj(lam2).
// => A[0,1]=A[0,2]=A[1,0]=A[2,0]=0 blocks (z - conj(z) is purely imaginary)
//    A[0,0](i)                       = lam1 + 2*real_part            (= d1)
//    A[1,1]=A[1,2]=A[2,1]=A[2,2](i)  = 2*|v2|^2*real_part            (= d2)
// W = (A - 0.97 I)/0.03.
// Outputs: A (23.04M f32), W (23.04M), c_pos (1600), k (1600) = 184.3 MB.
// Pure HBM-write-bound. Single flat grid-stride kernel mirroring the
// rocclr fillBuffer shape (2048x256, dwordx4 stores), with a rare branch
// (16K of 11.5M float4s) patching the nonzeros inline.

constexpr int       GN   = 40;
constexpr int       G    = GN * GN;              // 1600
constexpr int       S    = 3 * G;                // 4800
constexpr long long SS   = (long long)S * S;     // 23,040,000
constexpr unsigned  ROW4 = S / 4;                // 1200 float4 per row
constexpr unsigned  SS4  = (unsigned)(SS / 4);   // 5,760,000 float4 per matrix
constexpr unsigned  TOT4 = 2 * SS4 + (2 * G) / 4;  // 11,520,800 total float4

__device__ __forceinline__ float softplus_f(float x) {
    // jax.nn.softplus = max(x,0) + log1p(exp(-|x|))
    return fmaxf(x, 0.0f) + log1pf(expf(-fabsf(x)));
}

__global__ __launch_bounds__(256) void eigen_flat_kernel(
        const float* __restrict__ c,
        const float* __restrict__ k,
        const float* __restrict__ kp,
        float* __restrict__ out) {
    unsigned i      = blockIdx.x * 256u + threadIdx.x;
    unsigned stride = gridDim.x * 256u;
    float4* __restrict__ out4 = (float4*)out;

    for (; i < TOT4; i += stride) {
        if (i >= 2 * SS4) {
            // tail: c_pos (1600 floats) then k passthrough (1600 floats)
            unsigned base = (i - 2 * SS4) * 4;   // 0..3196
            float4 v;
            float* vv = &v.x;
#pragma unroll
            for (int j = 0; j < 4; ++j) {
                unsigned idx = base + j;
                vv[j] = (idx < (unsigned)G) ? softplus_f(c[idx]) : k[idx - G];
            }
            out4[i] = v;
            continue;
        }

        bool     isW = i >= SS4;
        unsigned fr  = isW ? i - SS4 : i;        // float4 index within matrix
        unsigned r   = fr / ROW4;                // row 0..4799 (magic mul)
        unsigned i4  = fr - r * ROW4;            // float4-col 0..1199
        unsigned b   = r / (unsigned)G;          // block-row 0..2
        unsigned g   = r - b * (unsigned)G;      // grid index

        // float4-col indices that can hold nonzeros for this row
        unsigned q1, q2;
        if (b == 0) { q1 = g >> 2;                   q2 = 0xffffffffu; }
        else        { q1 = ((unsigned)G + g) >> 2;   q2 = (2u * G + g) >> 2; }

        float4 v = make_float4(0.f, 0.f, 0.f, 0.f);

        if (i4 == q1 || i4 == q2) {              // rare: 16000 / 11.5M float4s
            float c_pos = softplus_f(c[g]);
            float k_x   = softplus_f(k[g]);
            float kp_p  = softplus_f(kp[g]);

            const float xi = 1.57079632679489662f;   // float32(pi/2), DT=1
            float okx  = 1.0f + k_x;
            float okp  = 1.0f + kp_p;
            float lam1 = 1.0f / okx;
            float rp   = 0.5f * (1.0f / okp + lam1);     // Re(lam2)
            float im   = c_pos * xi / sqrtf(okp * okx);  // Im(lam2)
            float ar   = rp - lam1 + 1e-6f;              // Re(alpha)
            float bx   = lam1 * xi;                      // beta*xi
            float v2sq = bx * bx / (ar * ar + im * im);  // |v2|^2

            float d1 = lam1 + 2.0f * rp;
            float d2 = 2.0f * v2sq * rp;

            const float INV_L = 1.0f / 0.03f;
            const float OML   = 0.97f;

            // columns and values for this row
            unsigned c1, c2;
            float    v1, v2v;
            if (b == 0) {
                c1 = g;                 v1  = isW ? (d1 - OML) * INV_L : d1;
                c2 = 0xffffffffu;       v2v = 0.0f;
            } else if (b == 1) {
                c1 = (unsigned)G + g;   v1  = isW ? (d2 - OML) * INV_L : d2;  // diag
                c2 = 2u * G + g;        v2v = isW ? d2 * INV_L : d2;          // off
            } else {
                c1 = (unsigned)G + g;   v1  = isW ? d2 * INV_L : d2;          // off
                c2 = 2u * G + g;        v2v = isW ? (d2 - OML) * INV_L : d2;  // diag
            }

            unsigned c0 = i4 * 4;
            float* vv = &v.x;
#pragma unroll
            for (int j = 0; j < 4; ++j) {
                unsigned col = c0 + j;
                if (col == c1)      vv[j] = v1;
                else if (col == c2) vv[j] = v2v;
            }
        }

        out4[i] = v;
    }
}

extern "C" void kernel_launch(void* const* d_in, const int* in_sizes, int n_in,
                              void* d_out, int out_size, void* d_ws, size_t ws_size,
                              hipStream_t stream) {
    const float* c  = (const float*)d_in[0];
    const float* k  = (const float*)d_in[1];
    const float* kp = (const float*)d_in[2];
    float* out = (float*)d_out;

    eigen_flat_kernel<<<2048, 256, 0, stream>>>(c, k, kp, out);
}